// Round 6
// baseline (885.307 us; speedup 1.0000x reference)
//
#include <hip/hip_runtime.h>
#include <hip/hip_cooperative_groups.h>
#include <math.h>

#define BB 8
#define TT 128
#define NN 512
#define HH 4
#define DD 2048      // N*HID
#define EE 16384
#define KTOT 4096    // 2048 (x) + 2048 (h)
#define NKB 128      // KTOT/32 kblocks
#define XROW 4112    // 4096 + 16 pad shorts (32 B) per batch row in LDS

typedef __attribute__((ext_vector_type(8))) short short8;
typedef __attribute__((ext_vector_type(4))) float f32x4;
typedef __attribute__((ext_vector_type(4))) unsigned int u32x4;

__device__ __forceinline__ float b2f(unsigned short u) {
    union { unsigned int i; float f; } v; v.i = ((unsigned int)u) << 16; return v.f;
}
__device__ __forceinline__ unsigned short f2b(float f) {
    union { float f; unsigned int i; } v; v.f = f;
    unsigned int r = v.i + 0x7fff + ((v.i >> 16) & 1);
    return (unsigned short)(r >> 16);
}
// fast sigmoid/tanh on v_exp_f32 + v_rcp_f32 (~4 ULP; proven R5, absmax 0.0117)
__device__ __forceinline__ float fsig(float z) {
    return __builtin_amdgcn_rcpf(1.f + __expf(-z));
}
__device__ __forceinline__ float ftanh(float z) {
    return 1.f - 2.f * __builtin_amdgcn_rcpf(1.f + __expf(2.f * z));
}

// ------- CSR build (one block, LDS atomics) + h ring init folded in -------

__global__ __launch_bounds__(1024) void k_csr_build(const int* __restrict__ ei,
                                                    int* __restrict__ offs,
                                                    int* __restrict__ csr_src,
                                                    unsigned int* __restrict__ hb) {
    __shared__ int cnt[NN];
    __shared__ int off[NN];
    __shared__ int fill[NN];
    const int tid = threadIdx.x;
    // hb0 (8192 dw) = h_0 zeros, tag bit0 = 0 -> passes at t=0.
    // hb1 (8192 dw) = 0xFFFFFFFF, tag bit0 = 1 -> pending until h_1 lands.
    for (int i = tid; i < 16384; i += 1024) hb[i] = (i < 8192) ? 0u : 0xFFFFFFFFu;
    if (tid < NN) { cnt[tid] = 0; fill[tid] = 0; }
    __syncthreads();
    for (int e = tid; e < EE; e += 1024) atomicAdd(&cnt[ei[EE + e]], 1);
    __syncthreads();
    if (tid < NN) off[tid] = cnt[tid];
    __syncthreads();
#pragma unroll
    for (int o = 1; o < NN; o <<= 1) {
        int v = 0;
        if (tid < NN && tid >= o) v = off[tid - o];
        __syncthreads();
        if (tid < NN) off[tid] += v;
        __syncthreads();
    }
    if (tid < NN) offs[tid + 1] = off[tid];   // inclusive sums
    if (tid == 0) offs[0] = 0;
    __syncthreads();
    for (int e = tid; e < EE; e += 1024) {
        int d = ei[EE + e];
        int pos = atomicAdd(&fill[d], 1);
        csr_src[(off[d] - cnt[d]) + pos] = ei[e];
    }
}

// ---------------- GAT (outputs bf16 seq[t][b][d]) ----------------

__global__ void k_gat0(const float* __restrict__ xseq, const float* __restrict__ W,
                       const float* __restrict__ as, const float* __restrict__ ad,
                       const float* __restrict__ bias, const int* __restrict__ offs,
                       const int* __restrict__ csr_src, unsigned short* __restrict__ seqout) {
    __shared__ float xr[NN];
    const int t = blockIdx.x;
    const int j = threadIdx.x;
    xr[j] = xseq[t * NN + j];
    __syncthreads();

    const float w0 = W[0], w1 = W[1], w2 = W[2], w3 = W[3];
    const float cs = w0 * as[0] + w1 * as[1] + w2 * as[2] + w3 * as[3];
    const float cd = w0 * ad[0] + w1 * ad[1] + w2 * ad[2] + w3 * ad[3];

    const float xj = xr[j];
    const float ed = cd * xj;
    float e0 = (cs + cd) * xj;
    e0 = e0 > 0.f ? e0 : 0.2f * e0;

    const int s0 = offs[j], s1 = offs[j + 1];
    float m = e0;
    for (int p = s0; p < s1; ++p) {
        float e = cs * xr[csr_src[p]] + ed;
        e = e > 0.f ? e : 0.2f * e;
        m = fmaxf(m, e);
    }
    float den = __expf(e0 - m);
    float num = den * xj;
    for (int p = s0; p < s1; ++p) {
        int s = csr_src[p];
        float e = cs * xr[s] + ed;
        e = e > 0.f ? e : 0.2f * e;
        float wgt = __expf(e - m);
        den += wgt;
        num += wgt * xr[s];
    }
    const float y = num / den;

    ushort4 o;
    o.x = f2b(fmaxf(w0 * y + bias[0], 0.f));
    o.y = f2b(fmaxf(w1 * y + bias[1], 0.f));
    o.z = f2b(fmaxf(w2 * y + bias[2], 0.f));
    o.w = f2b(fmaxf(w3 * y + bias[3], 0.f));
    *(ushort4*)(seqout + (size_t)t * BB * DD + (size_t)j * HH) = o;
}

__global__ void k_gat_rest(const float* __restrict__ xseq, const float* __restrict__ W,
                           const float* __restrict__ bias, unsigned short* __restrict__ seqout) {
    int n = blockIdx.x * blockDim.x + threadIdx.x;
    int t = n / (7 * NN);
    int rem = n - t * (7 * NN);
    int b = 1 + rem / NN;
    int j = rem - (b - 1) * NN;
    float x = xseq[((size_t)b * TT + t) * NN + j];
    const float w0 = W[0], w1 = W[1], w2 = W[2], w3 = W[3];
    ushort4 o;
    o.x = f2b(fmaxf(w0 * x + bias[0], 0.f));
    o.y = f2b(fmaxf(w1 * x + bias[1], 0.f));
    o.z = f2b(fmaxf(w2 * x + bias[2], 0.f));
    o.w = f2b(fmaxf(w3 * x + bias[3], 0.f));
    *(ushort4*)(seqout + (size_t)t * BB * DD + (size_t)b * DD + (size_t)j * HH) = o;
}

// ---------------- weight pack: f32 -> bf16 B-fragment tiles ----------------
__global__ __launch_bounds__(256) void k_pack_w(const float* __restrict__ wih,
                                                const float* __restrict__ whh,
                                                unsigned short* __restrict__ WP) {
    const int pair = blockIdx.x * 4 + (threadIdx.x >> 6);  // (s,kb): 0..65535
    const int lane = threadIdx.x & 63;
    const int s = pair >> 7, kb = pair & 127;
    const int n = lane >> 2, quad = lane & 3;
    const int d = (s >> 1) * 8 + (s & 1) * 4 + (n & 3);
    const int row = (n >> 2) * 2048 + d;
    const int k = kb * 32 + quad * 8;
    const float* src = (k < 2048) ? (wih + (size_t)row * 2048 + k)
                                  : (whh + (size_t)row * 2048 + (k - 2048));
    unsigned int u[4];
#pragma unroll
    for (int p = 0; p < 4; ++p)
        u[p] = (unsigned int)f2b(src[2 * p]) | ((unsigned int)f2b(src[2 * p + 1]) << 16);
    ((uint4*)WP)[(size_t)pair * 64 + quad * 16 + n] = make_uint4(u[0], u[1], u[2], u[3]);
}

// ---------------- persistent LSTM: tagged-payload poll (no flags) ----------------
// 256 blocks x 1024 thr (cooperative). Block b: d0=8b..8b+7, strips 2b/2b+1.
// Protocol: producer's 8-B h stores carry the generation in bit0 of their low
// bf16 (tag = (t>>1)&1 distinguishes h_t from stale h_{t-2} in the ping-pong
// buffer). Consumers poll the PAYLOAD (one 16-B sc-bypass load per unit, both
// qword tags checked independently -> sound under 8-B tearing); the poll load
// IS the fetch. No flag array, no producer s_waitcnt drain, no B1 barrier.
// Own block's h is seeded into LDS by wave0 (consumers self-skip, except t=0
// where hb0's zeros pass the tag check for everyone).
// Soundness of ping-pong overwrite: producer publishing h_{t+1} implies it
// consumed all of h_t, which implies every block published h_t, which implies
// every block finished its global reads of h_{t-1} -> overwriting buf[(t+1)&1]
// (holding h_{t-1}) is safe. red[] safety: waves rewrite red only after
// B2(t+1), which wave0 reaches only after its epilogue reads of red(t).
__global__ __launch_bounds__(1024, 4) void k_lstm_persist(
    const unsigned short* __restrict__ seq, const uint4* __restrict__ WPq,
    const float* __restrict__ b_ih, const float* __restrict__ b_hh,
    unsigned short* __restrict__ hb0, unsigned short* __restrict__ hb1) {
    __shared__ unsigned short xh[8][XROW];  // 65792 B unique x||h image
    __shared__ float red[2][8][32][4];      // 8 KB k-partial D
    __shared__ float biasL[32];

    const int tid = threadIdx.x;
    const int wave = tid >> 6, lane = tid & 63;
    const int st = wave >> 3, ke = wave & 7;
    const int bx = blockIdx.x;
    const int d0 = bx * 8;
    const size_t sglob = (size_t)bx * 2 + st;

    if (tid < 32) {
        const int g = tid >> 3, dl = tid & 7;
        const int row = g * 2048 + d0 + dl;
        biasL[tid] = b_ih[row] + b_hh[row];
    }

    // load this wave's 16 weight fragments into registers (once)
    uint4 w[16];
    {
        const uint4* wp = WPq + (sglob * NKB + (size_t)ke * 16) * 64 + lane;
#pragma unroll
        for (int i = 0; i < 16; ++i) w[i] = wp[i * 64];
    }
    __syncthreads();

    // A-operand LDS read base for this lane: batch = lane&7, quad = lane>>4
    const unsigned short* arow = &xh[lane & 7][(lane >> 4) << 3];

    // poll-staging geometry: unit0 = (batch tid>>8, block tid&255), unit1 = +4 batches
    const int ub = tid >> 8;                // 0..3
    const int ucol = tid & 255;             // producing block index
    const size_t goff0 = (size_t)ub * DD + (size_t)ucol * 8;
    const size_t goff1 = goff0 + (size_t)4 * DD;
    unsigned short* lds0 = &xh[ub][2048 + ucol * 8];
    unsigned short* lds1 = &xh[ub + 4][2048 + ucol * 8];
    const bool selfu = (ucol == bx);

    float creg = 0.f;   // wave0 gate state: cell (b=lane>>3, d=d0+(lane&7))

    for (int t = 0; t < TT; ++t) {
        const unsigned short* xt = seq + (size_t)t * BB * DD;
        const unsigned short* hin = (t & 1) ? hb1 : hb0;
        unsigned short* hout = (t & 1) ? hb0 : hb1;
        const unsigned int etag = (unsigned int)(t >> 1) & 1u;

        // stage x part (k<2048), two-phase; overlaps the h arrival window
        uint4 xv[2];
#pragma unroll
        for (int i = 0; i < 2; ++i) {
            const int c = tid + 1024 * i;            // 2048 chunks of 16 B
            xv[i] = *(const uint4*)(xt + (c >> 8) * DD + ((c & 255) << 3));
        }
#pragma unroll
        for (int i = 0; i < 2; ++i) {
            const int c = tid + 1024 * i;
            *(uint4*)&xh[c >> 8][(c & 255) << 3] = xv[i];
        }

        // poll-stage h: tagged payload; each thread owns 2 16-B units.
        // Self units are seeded in LDS by wave0 (except t=0: zeros pass tag).
        if (!selfu || t == 0) {
            const void* p0 = (const void*)(hin + goff0);
            const void* p1 = (const void*)(hin + goff1);
            bool done0 = false, done1 = false;
            while (true) {
                u32x4 a, b;
                asm volatile(
                    "global_load_dwordx4 %0, %2, off sc0 sc1\n\t"
                    "global_load_dwordx4 %1, %3, off sc0 sc1\n\t"
                    "s_waitcnt vmcnt(0)"
                    : "=&v"(a), "=&v"(b) : "v"(p0), "v"(p1) : "memory");
                if (!done0 && ((((a[0] ^ etag) | (a[2] ^ etag)) & 1u) == 0u)) {
                    *(u32x4*)lds0 = a;
                    done0 = true;
                }
                if (!done1 && ((((b[0] ^ etag) | (b[2] ^ etag)) & 1u) == 0u)) {
                    *(u32x4*)lds1 = b;
                    done1 = true;
                }
                if (done0 && done1) break;
                __builtin_amdgcn_s_sleep(1);
            }
        }
        __syncthreads();   // B2: x + h staged

        f32x4 acc = {0.f, 0.f, 0.f, 0.f};
#pragma unroll
        for (int i = 0; i < 16; ++i) {
            const int kb = ke * 16 + i;
            short8 a = *(const short8*)(arow + (kb << 5));
            short8 b;
            __builtin_memcpy(&b, &w[i], 16);
            acc = __builtin_amdgcn_mfma_f32_16x16x32_bf16(a, b, acc, 0, 0, 0);
        }
        if (lane < 32) *(f32x4*)&red[st][ke][lane][0] = acc;
        __syncthreads();   // B3: partials ready

        // wave 0: fused reduce + gates + tagged publish (no drain, no flag);
        // other waves run ahead into t+1 stage/poll.
        if (wave == 0) {
            const int b = lane >> 3, dl = lane & 7;     // batch, local d
            const int l2b = ((b & 4) << 2) | (dl & 3);  // + g*4 per gate
            const int reg = b & 3;
            const int sst = dl >> 2;
            float z[4];
#pragma unroll
            for (int g = 0; g < 4; ++g) {
                float zz = biasL[g * 8 + dl];
#pragma unroll
                for (int kk = 0; kk < 8; ++kk)
                    zz += red[sst][kk][l2b + g * 4][reg];
                z[g] = zz;
            }
            const float si = fsig(z[0]);
            const float sf = fsig(z[1]);
            const float tg = ftanh(z[2]);
            const float so = fsig(z[3]);
            creg = sf * creg + si * tg;
            const float hval = so * ftanh(creg);
            const unsigned int etag2 = (unsigned int)((t + 1) >> 1) & 1u;

            const float hoth = __shfl_xor(hval, 1, 64);
            const unsigned int pk = (unsigned int)f2b(hval) |
                                    ((unsigned int)f2b(hoth) << 16);   // even dl: dims dl,dl+1
            const unsigned int pkB = __shfl_xor(pk, 2, 64);            // dl0:d23 dl4:d67
            const unsigned int pkT = (pk & ~1u) | etag2;               // tag low bf16
            if ((lane & 3) == 0) {    // dl in {0,4}: publish dims dl..dl+3 (8 B, atomic)
                const unsigned long long qw =
                    (unsigned long long)pkT | ((unsigned long long)pkB << 32);
                __hip_atomic_store((unsigned long long*)(hout + (size_t)b * DD + d0 + dl),
                                   qw, __ATOMIC_RELAXED, __HIP_MEMORY_SCOPE_AGENT);
            }
            // seed own 16-B unit (per batch) into next step's LDS image
            const unsigned int pkC = __shfl_xor(pk, 4, 64);            // dl0: d45
            const unsigned int pkD = __shfl_xor(pkB, 4, 64);           // dl0: d67
            if ((lane & 7) == 0 && t < TT - 1) {
                u32x4 v;
                v[0] = pkT; v[1] = pkB;
                v[2] = (pkC & ~1u) | etag2; v[3] = pkD;
                *(u32x4*)&xh[b][2048 + d0] = v;
            }
        }
    }
}

// ---------------- final linear: out[b,o] = h[b,:]·w_lin[o,:] + b_lin[o] ----------------
__global__ void k_final(const unsigned short* __restrict__ h, const float* __restrict__ w_lin,
                        const float* __restrict__ b_lin, float* __restrict__ out) {
    const int wave = threadIdx.x >> 6;
    const int lane = threadIdx.x & 63;
    const int o = blockIdx.x * 4 + wave;
    const float4* w4 = (const float4*)(w_lin + (size_t)o * DD);

    float acc[8];
#pragma unroll
    for (int b = 0; b < 8; ++b) acc[b] = 0.f;
#pragma unroll 2
    for (int it = 0; it < 8; ++it) {
        const int k4 = it * 64 + lane;
        float4 wv = w4[k4];
#pragma unroll
        for (int b = 0; b < 8; ++b) {
            ushort4 hv = *(const ushort4*)(h + (size_t)b * DD + 4 * (size_t)k4);
            acc[b] += wv.x * b2f(hv.x) + wv.y * b2f(hv.y) +
                      wv.z * b2f(hv.z) + wv.w * b2f(hv.w);
        }
    }
#pragma unroll
    for (int b = 0; b < 8; ++b) {
        float v = acc[b];
        v += __shfl_xor(v, 32, 64);
        v += __shfl_xor(v, 16, 64);
        v += __shfl_xor(v, 8, 64);
        v += __shfl_xor(v, 4, 64);
        v += __shfl_xor(v, 2, 64);
        v += __shfl_xor(v, 1, 64);
        acc[b] = v;
    }
    if (lane < 8) out[(size_t)lane * NN + o] = acc[lane] + b_lin[o];
}

// ---------------- launch ----------------

extern "C" void kernel_launch(void* const* d_in, const int* in_sizes, int n_in,
                              void* d_out, int out_size, void* d_ws, size_t ws_size,
                              hipStream_t stream) {
    const float* xseq  = (const float*)d_in[0];
    const float* gat_w = (const float*)d_in[1];
    const float* a_src = (const float*)d_in[2];
    const float* a_dst = (const float*)d_in[3];
    const float* g_b   = (const float*)d_in[4];
    const float* w_ih  = (const float*)d_in[5];
    const float* w_hh  = (const float*)d_in[6];
    const float* b_ih  = (const float*)d_in[7];
    const float* b_hh  = (const float*)d_in[8];
    const float* w_lin = (const float*)d_in[9];
    const float* b_lin = (const float*)d_in[10];
    const int*   eidx  = (const int*)d_in[11];
    float* out = (float*)d_out;

    // workspace layout
    unsigned short* seq = (unsigned short*)d_ws;                 // T*B*D bf16 (4 MB)
    unsigned short* WP  = seq + (size_t)TT * BB * DD;            // 64 MB packed weights
    unsigned short* hb0 = WP + (size_t)8192 * KTOT;              // B*D bf16
    unsigned short* hb1 = hb0 + BB * DD;                         // B*D bf16
    int* offs    = (int*)(hb1 + BB * DD);
    int* csr_src = offs + NN + 1;

    // CSR build + h ring init (single block, LDS atomics)
    k_csr_build<<<1, 1024, 0, stream>>>(eidx, offs, csr_src, (unsigned int*)hb0);

    // weight pack (bf16, B-frag swizzled; coalesced — off the critical chain)
    k_pack_w<<<16384, 256, 0, stream>>>(w_ih, w_hh, WP);

    // GAT -> seq (bf16)
    k_gat0<<<TT, NN, 0, stream>>>(xseq, gat_w, a_src, a_dst, g_b, offs, csr_src, seq);
    k_gat_rest<<<(TT * 7 * NN) / 256, 256, 0, stream>>>(xseq, gat_w, g_b, seq);

    // persistent cooperative LSTM, tagged-payload poll protocol
    {
        void* kargs[] = {
            (void*)&seq, (void*)&WP, (void*)&b_ih, (void*)&b_hh,
            (void*)&hb0, (void*)&hb1,
        };
        hipLaunchCooperativeKernel((const void*)k_lstm_persist, dim3(256), dim3(1024),
                                   kargs, 0, stream);
    }

    // final h (= h_128) is in buf[(127+1)&1] = hb0
    k_final<<<NN / 4, 256, 0, stream>>>(hb0, w_lin, b_lin, out);
}